// Round 11
// baseline (256.936 us; speedup 1.0000x reference)
//
#include <hip/hip_runtime.h>
#include <stdint.h>
#include <limits.h>

// Problem constants (reference: B=4, N=8192, C=64, OUT=64, KNN=36)
#define BB 4
#define NN 8192
#define CC 64
#define OUTD 64
#define KK 36
#define NPTS (BB * NN)          // 32768
#define NBIN 129                // bins 0..128 (0 and 128 are clamp catch-alls)
// t = signed(float_bits(d2)) >> 20 (arith); bin = med3_i32(t,960,1088) - 960.
//
// xyzw layout: PAIR-INTERLEAVED. For even j: 8 floats
//   [x_j, x_j1, y_j, y_j1, z_j, z_j1, w_j, w_j1]   (j1 = j+1; 32 B per pair)
//
// Ledger (HW-validated R0-R10):
//   R0/R2  k_knn SMEM s_load + pk math     -> fast (validated 135-137us x6)
//   R1     per-lane VMEM broadcast         -> 1.9x REGRESSION
//   R3     global_load_lds + ds_read       -> REGRESSION; DPP scan bug
//   R4/R5  4-buffer SGPR rotation          -> container died twice; QUARANTINED
//   R6-R8  k_att swizzle/float4/nt-store   -> ALL NULL (k_att is ~48us, fine)
//   R9     fusion att->knn                 -> REGRESSION (cross-batch L2
//          thrash, FETCH 4MB->180MB) but yielded the split: k_vfeat ~59us!
//   R10    k_vfeat scalar-chain rewrite    -> +9us REGRESSION: removed the
//          DS storm but serialized each point into a 64-deep fmaf chain
//          (old form had 8-chain ILP). Scalarization itself worked.
// R11: k_vfeat = wave-uniform s_load chunks (no DS) + 2-point ILP with
// 16-channel SGPR ping-pong (the knn LOADSET idiom, validated since R2).
// Per-point accumulation order EXACT (b0; c ascending; x,y,z) -> bit-
// identical vfeat. k_knn / k_att byte-identical to validated forms.

typedef float v2f __attribute__((ext_vector_type(2)));

static __device__ __forceinline__ int laneid() { return threadIdx.x & 63; }
static __device__ __forceinline__ int waveid_uniform() {
    return __builtin_amdgcn_readfirstlane((int)(threadIdx.x >> 6));
}
static __device__ __forceinline__ float rdlane_f(float v, int l) {
    return __int_as_float(__builtin_amdgcn_readlane(__float_as_int(v), l));
}
static __device__ __forceinline__ unsigned long long shflx_ull(
        unsigned long long v, int m) {
    uint32_t lo = (uint32_t)v, hi = (uint32_t)(v >> 32);
    lo = (uint32_t)__shfl_xor((int)lo, m, 64);
    hi = (uint32_t)__shfl_xor((int)hi, m, 64);
    return ((unsigned long long)hi << 32) | lo;
}
// DPP helper: VALU-pipe cross-lane (no LDS). ctrl/bound must be constants.
#define DPP_F(oldv, v, ctrl, bound) \
    __int_as_float(__builtin_amdgcn_update_dpp( \
        __float_as_int(oldv), __float_as_int(v), (ctrl), 0xf, 0xf, (bound)))

// 64-lane sum: result in lane 63 (lane-63 TOTAL correct with full row_mask;
// intermediate lanes are NOT a valid prefix - R3 lesson).
static __device__ __forceinline__ float wave_sum_dpp(float v) {
    v += DPP_F(0.0f, v, 0x111, true);   // row_shr:1
    v += DPP_F(0.0f, v, 0x112, true);   // row_shr:2
    v += DPP_F(0.0f, v, 0x114, true);   // row_shr:4
    v += DPP_F(0.0f, v, 0x118, true);   // row_shr:8
    v += DPP_F(0.0f, v, 0x142, true);   // row_bcast:15
    v += DPP_F(0.0f, v, 0x143, true);   // row_bcast:31
    return rdlane_f(v, 63);
}
// 64-lane max: OOB lanes keep old=v (no-op under max)
static __device__ __forceinline__ float wave_max_dpp(float v) {
    v = fmaxf(v, DPP_F(v, v, 0x111, false));
    v = fmaxf(v, DPP_F(v, v, 0x112, false));
    v = fmaxf(v, DPP_F(v, v, 0x114, false));
    v = fmaxf(v, DPP_F(v, v, 0x118, false));
    v = fmaxf(v, DPP_F(v, v, 0x142, false));
    v = fmaxf(v, DPP_F(v, v, 0x143, false));
    return rdlane_f(v, 63);
}

// ---------------------------------------------------------------------------
// Kernel 1 (R11): v_feat = relu([feature, xyz] @ W_v + b_v) + xp.
// One wave handles 8 points (4 pairs). Block = 256 = 4 waves. grid = NPTS/32.
// Wv resident in 67 VGPRs. Feature rows via wave-uniform s_load_dwordx16
// chunks, 2 points in flight (2 fma chains), explicit A/B ping-pong:
//   load(A,ch0) load(B,ch1) consume(A) load(A,ch2) consume(B) load(B,ch3)
//   consume(A) consume(B)
// -> each lgkm drain covered by one 32-fma body; zero DS ops in hot loop.
// ---------------------------------------------------------------------------
#define LOAD16(D, P) do { \
        _Pragma("unroll") \
        for (int _k = 0; _k < 16; ++_k) (D)[_k] = (P)[_k]; } while (0)

__global__ __launch_bounds__(256) void k_vfeat(
    const float* __restrict__ feat, const float* __restrict__ xyz,
    const float* __restrict__ Wv, const float* __restrict__ bv,
    float* __restrict__ vfeat, float* __restrict__ xp)   // xp: interleaved xyzw
{
    __shared__ float xb[4][8][3];
    const int lane = laneid();
    const int wv = waveid_uniform();
    const int pbase = blockIdx.x * 32 + wv * 8;

    if (lane < 24)
        xb[wv][lane / 3][lane % 3] = xyz[pbase * 3 + lane];
    // same-wave LDS write->read: in-order per wave, compiler inserts lgkmcnt

    // weights resident in VGPRs (67 regs), loaded once per wave (L1/L2-hot)
    float wj[67];
    #pragma unroll
    for (int c = 0; c < 67; ++c) wj[c] = Wv[c * OUTD + lane];
    const float b0 = bv[lane];

    #pragma unroll 1
    for (int u = 0; u < 4; ++u) {                   // 4 point-pairs
        const int p0 = pbase + 2 * u;
        const float* __restrict__ R0 = feat + (size_t)p0 * CC;  // uniform
        const float* __restrict__ R1 = R0 + CC;                 // uniform

        float A0[16], A1[16], B0[16], B1[16];       // SGPR chunk buffers
        float a0 = b0, a1 = b0;

        LOAD16(A0, R0);      LOAD16(A1, R1);        // ch0
        LOAD16(B0, R0 + 16); LOAD16(B1, R1 + 16);   // ch1
        #pragma unroll
        for (int k = 0; k < 16; ++k) {              // consume ch0
            a0 = fmaf(A0[k], wj[k], a0);
            a1 = fmaf(A1[k], wj[k], a1);
        }
        LOAD16(A0, R0 + 32); LOAD16(A1, R1 + 32);   // ch2
        #pragma unroll
        for (int k = 0; k < 16; ++k) {              // consume ch1
            a0 = fmaf(B0[k], wj[16 + k], a0);
            a1 = fmaf(B1[k], wj[16 + k], a1);
        }
        LOAD16(B0, R0 + 48); LOAD16(B1, R1 + 48);   // ch3
        #pragma unroll
        for (int k = 0; k < 16; ++k) {              // consume ch2
            a0 = fmaf(A0[k], wj[32 + k], a0);
            a1 = fmaf(A1[k], wj[32 + k], a1);
        }
        #pragma unroll
        for (int k = 0; k < 16; ++k) {              // consume ch3
            a0 = fmaf(B0[k], wj[48 + k], a0);
            a1 = fmaf(B1[k], wj[48 + k], a1);
        }
        // xyz tail (same order as validated form)
        a0 = fmaf(xb[wv][2 * u][0],     wj[64], a0);
        a0 = fmaf(xb[wv][2 * u][1],     wj[65], a0);
        a0 = fmaf(xb[wv][2 * u][2],     wj[66], a0);
        a1 = fmaf(xb[wv][2 * u + 1][0], wj[64], a1);
        a1 = fmaf(xb[wv][2 * u + 1][1], wj[65], a1);
        a1 = fmaf(xb[wv][2 * u + 1][2], wj[66], a1);
        vfeat[(size_t)p0 * OUTD + lane]       = fmaxf(a0, 0.0f);
        vfeat[(size_t)(p0 + 1) * OUTD + lane] = fmaxf(a1, 0.0f);
    }

    if (lane < 8) {
        const int p = pbase + lane;
        const float x = xb[wv][lane][0], y = xb[wv][lane][1], z = xb[wv][lane][2];
        const float sq = (x * x + y * y) + z * z;
        const int base = (p >> 1) * 8 + (p & 1);    // pair-interleaved slot
        xp[base + 0] = x;
        xp[base + 2] = y;
        xp[base + 4] = z;
        xp[base + 6] = sq;
    }
}

// ---------------------------------------------------------------------------
// Kernel 2: 36-NN via per-query float-bit histogram selection.
// 512 blocks x 1024 thr, 64 queries/block (lane-per-query), 2 blocks/CU.
// BYTE-IDENTICAL to the R2-validated version (135-137us, absmax 0.0 x6).
// ---------------------------------------------------------------------------
__global__ __launch_bounds__(1024, 8) void k_knn(
    const float* __restrict__ xpAll, int* __restrict__ idx_ws)
{
    __shared__ __align__(16) uint32_t hist[NBIN * 64];          // 33.0 KB
    __shared__ __align__(16) unsigned long long buf2[64][65];   // 33.3 KB
    __shared__ int binB[64];
    __shared__ int cumLoA[64];
    __shared__ uint32_t bufCnt[64];
    __shared__ uint32_t dirCnt[64];

    const int lane = laneid();
    const int wv = waveid_uniform();               // 0..15
    const int batch = blockIdx.x >> 7;             // 128 blocks per batch
    const int qbase = (blockIdx.x & 127) << 6;
    const int q = qbase + lane;                    // local query id 0..8191
    const float* __restrict__ xp = xpAll + (size_t)batch * NN * 4;
    const v2f* __restrict__ X2 = (const v2f*)xp;   // pair h -> X2[4h..4h+3]

    // per-lane query fetch from the interleaved layout (once per block)
    const int pr = q >> 1, sub0 = q & 1;
    const float Qx = xp[pr * 8 + sub0 + 0];
    const float Qy = xp[pr * 8 + sub0 + 2];
    const float Qz = xp[pr * 8 + sub0 + 4];
    const float Qw = xp[pr * 8 + sub0 + 6];
    const v2f qx = { Qx, Qx };
    const v2f qy = { Qy, Qy };
    const v2f qz = { Qz, Qz };
    const v2f qw = { Qw, Qw };
    const v2f m2 = { -2.0f, -2.0f };

    const int h0 = wv * 256;                       // pair-index base (512 cands)
    const int laneAdj = lane - 960 * 64;           // fold bin rebase into addressing

    for (int i = threadIdx.x; i < NBIN * 64; i += 1024) hist[i] = 0u;
    if (threadIdx.x < 64) { bufCnt[threadIdx.x] = 0u; dirCnt[threadIdx.x] = 0u; }
    __syncthreads();

// one set = 4 pairs = 8 candidates = 128 B = 2x s_load_dwordx16 (wave-uniform)
#define LOADSET(S, si) do { \
        const v2f* _p = X2 + 4 * (h0 + 4 * (si)); \
        _Pragma("unroll") \
        for (int _k = 0; _k < 16; ++_k) (S)[_k] = _p[_k]; } while (0)

// distance math for pair j of a set (identical op sequence in both passes
// -> identical bits -> histogram/selection consistency)
#define PAIRD2(S, j, d2) \
        v2f _dot = __builtin_elementwise_fma(qx, (S)[4*(j)+0], \
                   __builtin_elementwise_fma(qy, (S)[4*(j)+1], \
                                             qz * (S)[4*(j)+2])); \
        v2f d2   = __builtin_elementwise_fma(m2, _dot, qw + (S)[4*(j)+3]);

#define P1SET(S) do { \
        _Pragma("unroll") \
        for (int _j = 0; _j < 4; ++_j) { \
            PAIRD2(S, _j, _d2) \
            int _t0 = ((int)__float_as_uint(_d2.x)) >> 20; \
            int _t1 = ((int)__float_as_uint(_d2.y)) >> 20; \
            int _b0 = min(max(_t0, 960), 1088);            /* v_med3_i32 */ \
            int _b1 = min(max(_t1, 960), 1088); \
            atomicAdd(&hist[_b0 * 64 + laneAdj], 1u); \
            atomicAdd(&hist[_b1 * 64 + laneAdj], 1u); \
        } } while (0)

    // ---- pass 1: histogram; ping-pong prefetch (sets 0..63; prefetch of
    // set 64 overruns this wave's chunk by 128 B -> still inside the
    // workspace (next chunk / next batch / vfeat region) -> safe.
    {
        v2f A[16], Bv[16];
        LOADSET(A, 0);
        #pragma unroll 1
        for (int it = 0; it < 32; ++it) {
            LOADSET(Bv, 2 * it + 1);
            P1SET(A);
            LOADSET(A, 2 * it + 2);
            P1SET(Bv);
        }
    }
    __syncthreads();

    // ---- find crossing bin (threads 0..63, one query each) ----
    if (threadIdx.x < 64) {
        int cum = 0, Bq = 128, cl = 0;
        for (int b2 = 0; b2 < NBIN; ++b2) {
            int c = (int)hist[b2 * 64 + threadIdx.x];
            if (cum + c >= KK) { Bq = b2; cl = cum; break; }
            cum += c;
        }
        binB[threadIdx.x] = Bq;
        cumLoA[threadIdx.x] = cl;
    }
    __syncthreads();

    // ---- per-lane BITS-domain thresholds for pass 2 ----
    const int Bq = binB[lane];
    const int TLb = (Bq > 0)    ? ((960 + Bq) << 20) : INT_MIN;
    const int THb = (Bq == 128) ? INT_MAX : (((960 + Bq + 1) << 20) - 1);
    const int grow = batch * NN + q;
    const int gBase = batch * NN;

#define EMIT(Bx, jj) do { \
        if ((Bx) <= THb) {                       /* rare (~1% of candidates) */ \
            if ((Bx) < TLb) { \
                uint32_t pos = atomicAdd(&dirCnt[lane], 1u); \
                idx_ws[grow * KK + (int)pos] = gBase + (jj); \
            } else { \
                uint32_t db = (uint32_t)max((Bx), 0);        /* exact key */ \
                uint32_t pos = atomicAdd(&bufCnt[lane], 1u); \
                if (pos < 64u) buf2[lane][(int)pos] = \
                    ((unsigned long long)db << 32) | (uint32_t)(jj); \
            } \
        } } while (0)

#define P2SET(S, si) do { \
        _Pragma("unroll") \
        for (int _j = 0; _j < 4; ++_j) { \
            PAIRD2(S, _j, _d2) \
            int _B0 = (int)__float_as_uint(_d2.x); \
            int _B1 = (int)__float_as_uint(_d2.y); \
            const int _jb = 2 * (h0 + 4 * (si) + _j); \
            EMIT(_B0, _jb + 0); \
            EMIT(_B1, _jb + 1); \
        } } while (0)

    // ---- pass 2: one-compare hot path; same ping-pong pipeline ----
    {
        v2f A[16], Bv[16];
        LOADSET(A, 0);
        #pragma unroll 1
        for (int it = 0; it < 32; ++it) {
            LOADSET(Bv, 2 * it + 1);
            P2SET(A, 2 * it);
            LOADSET(A, 2 * it + 2);
            P2SET(Bv, 2 * it + 1);
        }
    }
    __syncthreads();

#undef LOADSET
#undef PAIRD2
#undef P1SET
#undef P2SET
#undef EMIT

    // ---- final: pick (36 - cumLo) smallest exact keys from boundary bin.
    // Parallel across all 16 waves: wave wv owns queries 4wv..4wv+3; keys
    // one-per-lane; each pick is a 6-step shfl_xor 64-bit min-reduce.
    // Keys are unique (low 32 bits = candidate index) -> unique argmin.
    #pragma unroll 1
    for (int sub = 0; sub < 4; ++sub) {
        const int t = 4 * wv + sub;                 // wave-uniform query slot
        const int cl = cumLoA[t];
        const int r = KK - cl;                      // >= 1 always
        const int M = min((int)bufCnt[t], 64);
        const int q2 = qbase + t;
        const int outp = (batch * NN + q2) * KK + cl;
        unsigned long long key = (lane < M) ? buf2[t][lane] : ~0ULL;
        #pragma unroll 1
        for (int i = 0; i < r; ++i) {
            unsigned long long mk = key;
            #pragma unroll
            for (int d = 32; d >= 1; d >>= 1) {
                unsigned long long o = shflx_ull(mk, d);
                mk = (o < mk) ? o : mk;
            }
            int jj = (mk == ~0ULL) ? q2 : (int)(uint32_t)(mk & 0xFFFFFFFFu);
            if (jj < 0 || jj >= NN) jj = q2;         // pathological fallback
            if (lane == 0) idx_ws[outp + i] = batch * NN + jj;
            if (key == mk) key = ~0ULL;              // retire the winner
        }
    }
}

// ---------------------------------------------------------------------------
// Kernel 3: attention + projection — R8-validated form (absmax 0.0), scalar
// gathers + nontemporal out stores. grid = NPTS/4 blocks of 256, one point
// per wave. Standalone grid keeps the resident window inside one batch
// (R9 lesson: fusing destroyed this locality -> FETCH 4MB->180MB).
// ---------------------------------------------------------------------------
#define IDX(k) ((((k) & 3) == 0 ? I[(k) >> 2].x : ((k) & 3) == 1 ? I[(k) >> 2].y : \
                 ((k) & 3) == 2 ? I[(k) >> 2].z : I[(k) >> 2].w) & (NPTS - 1))

__global__ __launch_bounds__(256) void k_att(
    const float* __restrict__ feat, const float* __restrict__ vfeat,
    const int* __restrict__ idxw, const float* __restrict__ Wsuf,
    const float* __restrict__ bsuf, float* __restrict__ out)
{
    __shared__ float G[4][KK][33];   // 19,008 B (stride 33 == 1 mod 32: <=2-way)
    const int lane = laneid();
    const int wv = waveid_uniform();
    const int p = blockIdx.x * 4 + wv;

    // preload all 36 neighbor indices (wave-uniform s_load)
    const int4* __restrict__ myidx4 = (const int4*)(idxw + p * KK);
    int4 I[9];
    #pragma unroll
    for (int t = 0; t < 9; ++t) I[t] = myidx4[t];

    const float* __restrict__ Fp = feat + (size_t)p * CC;  // uniform -> s_load

    const int half = lane >> 5;       // 0: rows 2kk, 1: rows 2kk+1
    const int cpart = lane & 31;      // column within the 32-wide half

    float a = 0.0f;
    #pragma unroll
    for (int h = 0; h < 2; ++h) {
        // stage half h: 18 wave-loads, each covering two rows' 32-col halves
        #pragma unroll
        for (int kk = 0; kk < 18; ++kk) {
            int jrow = half ? IDX(2 * kk + 1) : IDX(2 * kk);
            G[wv][2 * kk + half][cpart] = feat[(size_t)jrow * CC + h * 32 + cpart];
        }
        // partial logits over this channel half (lane = k < 36); F is scalar
        if (lane < KK) {
            #pragma unroll 8
            for (int c = 0; c < 32; ++c)
                a = fmaf(Fp[h * 32 + c], G[wv][lane][c], a);
        }
    }
    const float logit = (lane < KK) ? a : -1e30f;

    // softmax across the 36 logit lanes — DPP (VALU pipe), no LDS
    const float m = wave_max_dpp(logit);
    const float e = (lane < KK) ? __expf(logit - m) : 0.0f;
    const float s = wave_sum_dpp(e);
    const float w = e * __frcp_rn(s);            // per-lane weight (0 for >=36)

    // weighted V gather: lane = channel; weight broadcast via v_readlane
    float acc = 0.0f;
    #pragma unroll
    for (int k = 0; k < KK; ++k) {
        float wk = rdlane_f(w, k);
        int j = IDX(k);
        acc = fmaf(wk, vfeat[j * OUTD + lane], acc);
    }

    // projection: o[lane] = b[lane] + sum_c acc_c * Wsuf[c][lane]
    float o = bsuf[lane];
    #pragma unroll 8
    for (int c = 0; c < OUTD; ++c) {
        float ac = rdlane_f(acc, c);
        o = fmaf(ac, Wsuf[c * OUTD + lane], o);
    }
    // nontemporal: no L2 allocation for the streaming output (validated R8)
    __builtin_nontemporal_store(o, &out[(size_t)p * OUTD + lane]);

    if (p == 0 && lane == 0) out[(size_t)NPTS * OUTD] = (float)NN;  // scalar N
}

// ---------------------------------------------------------------------------
extern "C" void kernel_launch(void* const* d_in, const int* in_sizes, int n_in,
                              void* d_out, int out_size, void* d_ws, size_t ws_size,
                              hipStream_t stream)
{
    const float* feat = (const float*)d_in[0];
    const float* xyz  = (const float*)d_in[1];
    const float* Wv   = (const float*)d_in[2];
    const float* bv   = (const float*)d_in[3];
    const float* Wsuf = (const float*)d_in[4];
    const float* bsuf = (const float*)d_in[5];
    float* out = (float*)d_out;

    char* ws = (char*)d_ws;
    float* xp = (float*)ws;                                   // 512 KB interleaved
    float*  vfeat = (float*)(ws + (512 << 10));               // 8 MB
    int*    idxw  = (int*)(ws + (512 << 10) + (8 << 20));     // 4.5 MB

    k_vfeat<<<NPTS / 32, 256, 0, stream>>>(feat, xyz, Wv, bv, vfeat, xp);
    k_knn  <<<NPTS / 64, 1024, 0, stream>>>(xp, idxw);
    k_att  <<<NPTS / 4, 256, 0, stream>>>(feat, vfeat, idxw, Wsuf, bsuf, out);
}

// Round 12
// 244.939 us; speedup vs baseline: 1.0490x; 1.0490x over previous
//
#include <hip/hip_runtime.h>
#include <stdint.h>
#include <limits.h>

// Problem constants (reference: B=4, N=8192, C=64, OUT=64, KNN=36)
#define BB 4
#define NN 8192
#define CC 64
#define OUTD 64
#define KK 36
#define NPTS (BB * NN)          // 32768
#define NBIN 129                // bins 0..128 (0 and 128 are clamp catch-alls)
// t = signed(float_bits(d2)) >> 20 (arith); bin = med3_i32(t,960,1088) - 960.
//
// xyzw layout: PAIR-INTERLEAVED. For even j: 8 floats
//   [x_j, x_j1, y_j, y_j1, z_j, z_j1, w_j, w_j1]   (j1 = j+1; 32 B per pair)
//
// Ledger (HW-validated R0-R11):
//   R0/R2  k_knn SMEM s_load + pk math     -> fast (validated 135-137us x7)
//   R1     per-lane VMEM broadcast         -> 1.9x REGRESSION
//   R3     global_load_lds + ds_read       -> REGRESSION; DPP scan bug
//   R4/R5  4-buffer SGPR rotation          -> container died twice; QUARANTINED
//   R6-R8  k_att swizzle/float4/nt-store   -> ALL NULL (k_att ~48us, fine)
//   R9     fusion att->knn                 -> REGRESSION (cross-batch L2
//          thrash) but yielded the split: k_vfeat ~59us, k_att ~48us
//   R10    k_vfeat scalar-chain (s_load)   -> +8us  REGRESSION
//   R11    k_vfeat 2-pt ping-pong (s_load) -> +14us REGRESSION (worse with
//          more buffers -> fetch mechanism is the problem, not ILP)
// R12: the feature row is ALREADY in wave registers after one coalesced
// load. Broadcast per-channel values with v_readlane (VALU pipe, zero
// memory ops) -- the idiom k_att's projection loop already validates fast.
// 512 readlane + 512 fma per wave, 8 independent chains, Wv in 67 VGPRs.
// Accumulation order EXACT (b0; c ascending; xyz tail) -> bit-identical
// vfeat. k_knn / k_att byte-identical to R8 (242.9us, absmax 0.0).

typedef float v2f __attribute__((ext_vector_type(2)));

static __device__ __forceinline__ int laneid() { return threadIdx.x & 63; }
static __device__ __forceinline__ int waveid_uniform() {
    return __builtin_amdgcn_readfirstlane((int)(threadIdx.x >> 6));
}
static __device__ __forceinline__ float rdlane_f(float v, int l) {
    return __int_as_float(__builtin_amdgcn_readlane(__float_as_int(v), l));
}
static __device__ __forceinline__ unsigned long long shflx_ull(
        unsigned long long v, int m) {
    uint32_t lo = (uint32_t)v, hi = (uint32_t)(v >> 32);
    lo = (uint32_t)__shfl_xor((int)lo, m, 64);
    hi = (uint32_t)__shfl_xor((int)hi, m, 64);
    return ((unsigned long long)hi << 32) | lo;
}
// DPP helper: VALU-pipe cross-lane (no LDS). ctrl/bound must be constants.
#define DPP_F(oldv, v, ctrl, bound) \
    __int_as_float(__builtin_amdgcn_update_dpp( \
        __float_as_int(oldv), __float_as_int(v), (ctrl), 0xf, 0xf, (bound)))

// 64-lane sum: result in lane 63 (lane-63 TOTAL correct with full row_mask;
// intermediate lanes are NOT a valid prefix - R3 lesson).
static __device__ __forceinline__ float wave_sum_dpp(float v) {
    v += DPP_F(0.0f, v, 0x111, true);   // row_shr:1
    v += DPP_F(0.0f, v, 0x112, true);   // row_shr:2
    v += DPP_F(0.0f, v, 0x114, true);   // row_shr:4
    v += DPP_F(0.0f, v, 0x118, true);   // row_shr:8
    v += DPP_F(0.0f, v, 0x142, true);   // row_bcast:15
    v += DPP_F(0.0f, v, 0x143, true);   // row_bcast:31
    return rdlane_f(v, 63);
}
// 64-lane max: OOB lanes keep old=v (no-op under max)
static __device__ __forceinline__ float wave_max_dpp(float v) {
    v = fmaxf(v, DPP_F(v, v, 0x111, false));
    v = fmaxf(v, DPP_F(v, v, 0x112, false));
    v = fmaxf(v, DPP_F(v, v, 0x114, false));
    v = fmaxf(v, DPP_F(v, v, 0x118, false));
    v = fmaxf(v, DPP_F(v, v, 0x142, false));
    v = fmaxf(v, DPP_F(v, v, 0x143, false));
    return rdlane_f(v, 63);
}

// ---------------------------------------------------------------------------
// Kernel 1 (R12): v_feat = relu([feature, xyz] @ W_v + b_v) + xp.
// One wave handles 8 points. Block = 256 = 4 waves. grid = NPTS/32.
// Feature rows loaded ONCE coalesced (8 VMEM); per-channel broadcast via
// v_readlane (VALU, zero memory ops in the GEMV loop); Wv in 67 VGPRs.
// 8 independent fma chains (original ILP). Accumulation order EXACT.
// ---------------------------------------------------------------------------
__global__ __launch_bounds__(256) void k_vfeat(
    const float* __restrict__ feat, const float* __restrict__ xyz,
    const float* __restrict__ Wv, const float* __restrict__ bv,
    float* __restrict__ vfeat, float* __restrict__ xp)   // xp: interleaved xyzw
{
    __shared__ float xb[4][8][3];
    const int lane = laneid();
    const int wv = waveid_uniform();
    const int pbase = blockIdx.x * 32 + wv * 8;

    if (lane < 24)
        xb[wv][lane / 3][lane % 3] = xyz[pbase * 3 + lane];
    // same-wave LDS write->read: in-order per wave, compiler inserts lgkmcnt

    // weights resident in VGPRs (67 regs), loaded once per wave (L1-hot)
    float wj[67];
    #pragma unroll
    for (int c = 0; c < 67; ++c) wj[c] = Wv[c * OUTD + lane];
    const float b0 = bv[lane];

    // coalesced per-lane feature rows: fr[pp] holds feat[pbase+pp][lane]
    float fr[8];
    #pragma unroll
    for (int pp = 0; pp < 8; ++pp)
        fr[pp] = feat[(size_t)(pbase + pp) * CC + lane];

    float acc[8];
    #pragma unroll
    for (int pp = 0; pp < 8; ++pp) acc[pp] = b0;

    // GEMV: c-outer / pp-inner (8 independent chains, as validated form);
    // feat[p][c] broadcast from lane c of fr[pp] via v_readlane (VALU).
    #pragma unroll
    for (int c = 0; c < CC; ++c) {
        #pragma unroll
        for (int pp = 0; pp < 8; ++pp)
            acc[pp] = fmaf(rdlane_f(fr[pp], c), wj[c], acc[pp]);
    }
    #pragma unroll
    for (int pp = 0; pp < 8; ++pp) {
        float a = acc[pp];
        a = fmaf(xb[wv][pp][0], wj[64], a);
        a = fmaf(xb[wv][pp][1], wj[65], a);
        a = fmaf(xb[wv][pp][2], wj[66], a);
        vfeat[(size_t)(pbase + pp) * OUTD + lane] = fmaxf(a, 0.0f);
    }

    if (lane < 8) {
        const int p = pbase + lane;
        const float x = xb[wv][lane][0], y = xb[wv][lane][1], z = xb[wv][lane][2];
        const float sq = (x * x + y * y) + z * z;
        const int base = (p >> 1) * 8 + (p & 1);    // pair-interleaved slot
        xp[base + 0] = x;
        xp[base + 2] = y;
        xp[base + 4] = z;
        xp[base + 6] = sq;
    }
}

// ---------------------------------------------------------------------------
// Kernel 2: 36-NN via per-query float-bit histogram selection.
// 512 blocks x 1024 thr, 64 queries/block (lane-per-query), 2 blocks/CU.
// BYTE-IDENTICAL to the R2-validated version (135-137us, absmax 0.0 x7).
// ---------------------------------------------------------------------------
__global__ __launch_bounds__(1024, 8) void k_knn(
    const float* __restrict__ xpAll, int* __restrict__ idx_ws)
{
    __shared__ __align__(16) uint32_t hist[NBIN * 64];          // 33.0 KB
    __shared__ __align__(16) unsigned long long buf2[64][65];   // 33.3 KB
    __shared__ int binB[64];
    __shared__ int cumLoA[64];
    __shared__ uint32_t bufCnt[64];
    __shared__ uint32_t dirCnt[64];

    const int lane = laneid();
    const int wv = waveid_uniform();               // 0..15
    const int batch = blockIdx.x >> 7;             // 128 blocks per batch
    const int qbase = (blockIdx.x & 127) << 6;
    const int q = qbase + lane;                    // local query id 0..8191
    const float* __restrict__ xp = xpAll + (size_t)batch * NN * 4;
    const v2f* __restrict__ X2 = (const v2f*)xp;   // pair h -> X2[4h..4h+3]

    // per-lane query fetch from the interleaved layout (once per block)
    const int pr = q >> 1, sub0 = q & 1;
    const float Qx = xp[pr * 8 + sub0 + 0];
    const float Qy = xp[pr * 8 + sub0 + 2];
    const float Qz = xp[pr * 8 + sub0 + 4];
    const float Qw = xp[pr * 8 + sub0 + 6];
    const v2f qx = { Qx, Qx };
    const v2f qy = { Qy, Qy };
    const v2f qz = { Qz, Qz };
    const v2f qw = { Qw, Qw };
    const v2f m2 = { -2.0f, -2.0f };

    const int h0 = wv * 256;                       // pair-index base (512 cands)
    const int laneAdj = lane - 960 * 64;           // fold bin rebase into addressing

    for (int i = threadIdx.x; i < NBIN * 64; i += 1024) hist[i] = 0u;
    if (threadIdx.x < 64) { bufCnt[threadIdx.x] = 0u; dirCnt[threadIdx.x] = 0u; }
    __syncthreads();

// one set = 4 pairs = 8 candidates = 128 B = 2x s_load_dwordx16 (wave-uniform)
#define LOADSET(S, si) do { \
        const v2f* _p = X2 + 4 * (h0 + 4 * (si)); \
        _Pragma("unroll") \
        for (int _k = 0; _k < 16; ++_k) (S)[_k] = _p[_k]; } while (0)

// distance math for pair j of a set (identical op sequence in both passes
// -> identical bits -> histogram/selection consistency)
#define PAIRD2(S, j, d2) \
        v2f _dot = __builtin_elementwise_fma(qx, (S)[4*(j)+0], \
                   __builtin_elementwise_fma(qy, (S)[4*(j)+1], \
                                             qz * (S)[4*(j)+2])); \
        v2f d2   = __builtin_elementwise_fma(m2, _dot, qw + (S)[4*(j)+3]);

#define P1SET(S) do { \
        _Pragma("unroll") \
        for (int _j = 0; _j < 4; ++_j) { \
            PAIRD2(S, _j, _d2) \
            int _t0 = ((int)__float_as_uint(_d2.x)) >> 20; \
            int _t1 = ((int)__float_as_uint(_d2.y)) >> 20; \
            int _b0 = min(max(_t0, 960), 1088);            /* v_med3_i32 */ \
            int _b1 = min(max(_t1, 960), 1088); \
            atomicAdd(&hist[_b0 * 64 + laneAdj], 1u); \
            atomicAdd(&hist[_b1 * 64 + laneAdj], 1u); \
        } } while (0)

    // ---- pass 1: histogram; ping-pong prefetch (sets 0..63; prefetch of
    // set 64 overruns this wave's chunk by 128 B -> still inside the
    // workspace (next chunk / next batch / vfeat region) -> safe.
    {
        v2f A[16], Bv[16];
        LOADSET(A, 0);
        #pragma unroll 1
        for (int it = 0; it < 32; ++it) {
            LOADSET(Bv, 2 * it + 1);
            P1SET(A);
            LOADSET(A, 2 * it + 2);
            P1SET(Bv);
        }
    }
    __syncthreads();

    // ---- find crossing bin (threads 0..63, one query each) ----
    if (threadIdx.x < 64) {
        int cum = 0, Bq = 128, cl = 0;
        for (int b2 = 0; b2 < NBIN; ++b2) {
            int c = (int)hist[b2 * 64 + threadIdx.x];
            if (cum + c >= KK) { Bq = b2; cl = cum; break; }
            cum += c;
        }
        binB[threadIdx.x] = Bq;
        cumLoA[threadIdx.x] = cl;
    }
    __syncthreads();

    // ---- per-lane BITS-domain thresholds for pass 2 ----
    const int Bq = binB[lane];
    const int TLb = (Bq > 0)    ? ((960 + Bq) << 20) : INT_MIN;
    const int THb = (Bq == 128) ? INT_MAX : (((960 + Bq + 1) << 20) - 1);
    const int grow = batch * NN + q;
    const int gBase = batch * NN;

#define EMIT(Bx, jj) do { \
        if ((Bx) <= THb) {                       /* rare (~1% of candidates) */ \
            if ((Bx) < TLb) { \
                uint32_t pos = atomicAdd(&dirCnt[lane], 1u); \
                idx_ws[grow * KK + (int)pos] = gBase + (jj); \
            } else { \
                uint32_t db = (uint32_t)max((Bx), 0);        /* exact key */ \
                uint32_t pos = atomicAdd(&bufCnt[lane], 1u); \
                if (pos < 64u) buf2[lane][(int)pos] = \
                    ((unsigned long long)db << 32) | (uint32_t)(jj); \
            } \
        } } while (0)

#define P2SET(S, si) do { \
        _Pragma("unroll") \
        for (int _j = 0; _j < 4; ++_j) { \
            PAIRD2(S, _j, _d2) \
            int _B0 = (int)__float_as_uint(_d2.x); \
            int _B1 = (int)__float_as_uint(_d2.y); \
            const int _jb = 2 * (h0 + 4 * (si) + _j); \
            EMIT(_B0, _jb + 0); \
            EMIT(_B1, _jb + 1); \
        } } while (0)

    // ---- pass 2: one-compare hot path; same ping-pong pipeline ----
    {
        v2f A[16], Bv[16];
        LOADSET(A, 0);
        #pragma unroll 1
        for (int it = 0; it < 32; ++it) {
            LOADSET(Bv, 2 * it + 1);
            P2SET(A, 2 * it);
            LOADSET(A, 2 * it + 2);
            P2SET(Bv, 2 * it + 1);
        }
    }
    __syncthreads();

#undef LOADSET
#undef PAIRD2
#undef P1SET
#undef P2SET
#undef EMIT

    // ---- final: pick (36 - cumLo) smallest exact keys from boundary bin.
    // Parallel across all 16 waves: wave wv owns queries 4wv..4wv+3; keys
    // one-per-lane; each pick is a 6-step shfl_xor 64-bit min-reduce.
    // Keys are unique (low 32 bits = candidate index) -> unique argmin.
    #pragma unroll 1
    for (int sub = 0; sub < 4; ++sub) {
        const int t = 4 * wv + sub;                 // wave-uniform query slot
        const int cl = cumLoA[t];
        const int r = KK - cl;                      // >= 1 always
        const int M = min((int)bufCnt[t], 64);
        const int q2 = qbase + t;
        const int outp = (batch * NN + q2) * KK + cl;
        unsigned long long key = (lane < M) ? buf2[t][lane] : ~0ULL;
        #pragma unroll 1
        for (int i = 0; i < r; ++i) {
            unsigned long long mk = key;
            #pragma unroll
            for (int d = 32; d >= 1; d >>= 1) {
                unsigned long long o = shflx_ull(mk, d);
                mk = (o < mk) ? o : mk;
            }
            int jj = (mk == ~0ULL) ? q2 : (int)(uint32_t)(mk & 0xFFFFFFFFu);
            if (jj < 0 || jj >= NN) jj = q2;         // pathological fallback
            if (lane == 0) idx_ws[outp + i] = batch * NN + jj;
            if (key == mk) key = ~0ULL;              // retire the winner
        }
    }
}

// ---------------------------------------------------------------------------
// Kernel 3: attention + projection — R8-validated form (absmax 0.0), scalar
// gathers + nontemporal out stores. grid = NPTS/4 blocks of 256, one point
// per wave. Standalone grid keeps the resident window inside one batch
// (R9 lesson: fusing destroyed this locality -> FETCH 4MB->180MB).
// ---------------------------------------------------------------------------
#define IDX(k) ((((k) & 3) == 0 ? I[(k) >> 2].x : ((k) & 3) == 1 ? I[(k) >> 2].y : \
                 ((k) & 3) == 2 ? I[(k) >> 2].z : I[(k) >> 2].w) & (NPTS - 1))

__global__ __launch_bounds__(256) void k_att(
    const float* __restrict__ feat, const float* __restrict__ vfeat,
    const int* __restrict__ idxw, const float* __restrict__ Wsuf,
    const float* __restrict__ bsuf, float* __restrict__ out)
{
    __shared__ float G[4][KK][33];   // 19,008 B (stride 33 == 1 mod 32: <=2-way)
    const int lane = laneid();
    const int wv = waveid_uniform();
    const int p = blockIdx.x * 4 + wv;

    // preload all 36 neighbor indices (wave-uniform s_load)
    const int4* __restrict__ myidx4 = (const int4*)(idxw + p * KK);
    int4 I[9];
    #pragma unroll
    for (int t = 0; t < 9; ++t) I[t] = myidx4[t];

    const float* __restrict__ Fp = feat + (size_t)p * CC;  // uniform -> s_load

    const int half = lane >> 5;       // 0: rows 2kk, 1: rows 2kk+1
    const int cpart = lane & 31;      // column within the 32-wide half

    float a = 0.0f;
    #pragma unroll
    for (int h = 0; h < 2; ++h) {
        // stage half h: 18 wave-loads, each covering two rows' 32-col halves
        #pragma unroll
        for (int kk = 0; kk < 18; ++kk) {
            int jrow = half ? IDX(2 * kk + 1) : IDX(2 * kk);
            G[wv][2 * kk + half][cpart] = feat[(size_t)jrow * CC + h * 32 + cpart];
        }
        // partial logits over this channel half (lane = k < 36); F is scalar
        if (lane < KK) {
            #pragma unroll 8
            for (int c = 0; c < 32; ++c)
                a = fmaf(Fp[h * 32 + c], G[wv][lane][c], a);
        }
    }
    const float logit = (lane < KK) ? a : -1e30f;

    // softmax across the 36 logit lanes — DPP (VALU pipe), no LDS
    const float m = wave_max_dpp(logit);
    const float e = (lane < KK) ? __expf(logit - m) : 0.0f;
    const float s = wave_sum_dpp(e);
    const float w = e * __frcp_rn(s);            // per-lane weight (0 for >=36)

    // weighted V gather: lane = channel; weight broadcast via v_readlane
    float acc = 0.0f;
    #pragma unroll
    for (int k = 0; k < KK; ++k) {
        float wk = rdlane_f(w, k);
        int j = IDX(k);
        acc = fmaf(wk, vfeat[j * OUTD + lane], acc);
    }

    // projection: o[lane] = b[lane] + sum_c acc_c * Wsuf[c][lane]
    float o = bsuf[lane];
    #pragma unroll 8
    for (int c = 0; c < OUTD; ++c) {
        float ac = rdlane_f(acc, c);
        o = fmaf(ac, Wsuf[c * OUTD + lane], o);
    }
    // nontemporal: no L2 allocation for the streaming output (validated R8)
    __builtin_nontemporal_store(o, &out[(size_t)p * OUTD + lane]);

    if (p == 0 && lane == 0) out[(size_t)NPTS * OUTD] = (float)NN;  // scalar N
}

// ---------------------------------------------------------------------------
extern "C" void kernel_launch(void* const* d_in, const int* in_sizes, int n_in,
                              void* d_out, int out_size, void* d_ws, size_t ws_size,
                              hipStream_t stream)
{
    const float* feat = (const float*)d_in[0];
    const float* xyz  = (const float*)d_in[1];
    const float* Wv   = (const float*)d_in[2];
    const float* bv   = (const float*)d_in[3];
    const float* Wsuf = (const float*)d_in[4];
    const float* bsuf = (const float*)d_in[5];
    float* out = (float*)d_out;

    char* ws = (char*)d_ws;
    float* xp = (float*)ws;                                   // 512 KB interleaved
    float*  vfeat = (float*)(ws + (512 << 10));               // 8 MB
    int*    idxw  = (int*)(ws + (512 << 10) + (8 << 20));     // 4.5 MB

    k_vfeat<<<NPTS / 32, 256, 0, stream>>>(feat, xyz, Wv, bv, vfeat, xp);
    k_knn  <<<NPTS / 64, 1024, 0, stream>>>(xp, idxw);
    k_att  <<<NPTS / 4, 256, 0, stream>>>(feat, vfeat, idxw, Wsuf, bsuf, out);
}